// Round 5
// baseline (265.710 us; speedup 1.0000x reference)
//
#include <hip/hip_runtime.h>

// FWHT along axis 1 of (64, 1024, 512) fp32, unnormalized (a+b, a-b), h=1..512.
// Round 6 resubmit (R4 bench was an infra failure: "container failed twice";
// kernel never executed). Two sequential passes instead of one strided pass.
// Evidence: four structurally different single-pass kernels (DC=16/32,
// pinned prefetch, direct stores) ALL plateau at 2.2-2.3 TB/s / 86-97 us with
// nothing on-chip saturated (VALU 7%, LDS conflicts 0, occupancy stable).
// The invariant is the ADDRESS STREAM: single-pass forces column-partitioned
// I/O -> 128-512 B chunks per 2 KB row at 2-32 KB stride ~= 35% DRAM
// efficiency (2.2/6.3). Fix the stream, not the schedule.
//
// Factorization: stages on disjoint index bits commute, so
//   H_1024 = H_16(bits 6..9)  o  H_64(bits 0..5).
// K1: H_64 over each 64-consecutive-row slab. A slab (b, n>>6) is a single
//     CONTIGUOUS 128 KB chunk of the array. 512 threads/block, thread owns
//     one column: u[64] in registers, loads/stores are full-2KB-row,
//     slab-sequential. No LDS. No barriers.
// K2: H_16 over rows {ghi*64 + r} (the high 4 bits), in-place on y.
//     128 threads/block, thread owns a float4 column x 16 rows; every wave
//     instruction covers 1 KB of a row, the block covers full 2 KB rows.
//     Row set {ghi*64+r} x all 512 cols is owned by exactly one block -> no
//     inter-block races; K1->K2 ordered by same-stream semantics.
// L3 (256 MB) interplay: K1's 128 MB write mostly stays resident; K2 re-reads
// it (L3 hits) and overwrites in place (no dead dirty evictions). Expected
// HBM ~250-380 MB at sequential efficiency vs 201 MB at 35%.
// Decisive test: K1 hbm_gbps >= 4 TB/s. If K1 also shows ~2.2 TB/s the
// granule theory is wrong and R5 (~89 us) was the roofline.

constexpr int NB = 64;    // batch
constexpr int NR = 1024;  // transform length (axis 1)
constexpr int ND = 512;   // inner dim

// ---------------- K1: H_64 on 64-row slabs (contiguous 128 KB) -------------
// grid = NB * (NR/64) = 64*16 = 1024 blocks, 512 threads.
__global__ __launch_bounds__(512)
void fwht_k1(const float* __restrict__ x, float* __restrict__ y) {
    const int c   = threadIdx.x;                 // column 0..511
    const int sid = blockIdx.x;                  // slab id 0..1023
    const size_t base = (size_t)sid * (64 * ND) + (size_t)c;

    float u[64];
#pragma unroll
    for (int i = 0; i < 64; ++i)
        u[i] = x[base + (size_t)i * ND];

    // H_64 over i (global stages h = 1..32)
#pragma unroll
    for (int hb = 1; hb < 64; hb <<= 1) {
#pragma unroll
        for (int i = 0; i < 64; ++i) {
            if ((i & hb) == 0) {
                const int k = i | hb;
                float a = u[i], bb = u[k];
                u[i] = a + bb;
                u[k] = a - bb;
            }
        }
    }

#pragma unroll
    for (int i = 0; i < 64; ++i)
        y[base + (size_t)i * ND] = u[i];
}

// ---------------- K2: H_16 over the high 4 bits, in place ------------------
// block = (b, r): rows n = ghi*64 + r, ghi in [0,16). 128 threads, thread
// owns cols 4q..4q+3. grid = NB * 64 = 4096 blocks.
__global__ __launch_bounds__(128)
void fwht_k2(float* __restrict__ y) {
    const int q   = threadIdx.x;                 // float4 column 0..127
    const int pid = blockIdx.x;                  // b*64 + r
    const int b   = pid >> 6;
    const int r   = pid & 63;
    const size_t base = ((size_t)b * NR + (size_t)r) * ND + (size_t)(q * 4);
    constexpr size_t RSTEP = (size_t)64 * ND;    // 64 rows = 32768 floats

    float4 v[16];
#pragma unroll
    for (int g = 0; g < 16; ++g)
        v[g] = *reinterpret_cast<const float4*>(&y[base + (size_t)g * RSTEP]);

    // H_16 over g (global stages h = 64,128,256,512)
#pragma unroll
    for (int hb = 1; hb < 16; hb <<= 1) {
#pragma unroll
        for (int g = 0; g < 16; ++g) {
            if ((g & hb) == 0) {
                const int k = g | hb;
                float4 a = v[g], bb = v[k];
                v[g] = make_float4(a.x + bb.x, a.y + bb.y, a.z + bb.z, a.w + bb.w);
                v[k] = make_float4(a.x - bb.x, a.y - bb.y, a.z - bb.z, a.w - bb.w);
            }
        }
    }

#pragma unroll
    for (int g = 0; g < 16; ++g)
        *reinterpret_cast<float4*>(&y[base + (size_t)g * RSTEP]) = v[g];
}

extern "C" void kernel_launch(void* const* d_in, const int* in_sizes, int n_in,
                              void* d_out, int out_size, void* d_ws, size_t ws_size,
                              hipStream_t stream) {
    const float* x = (const float*)d_in[0];
    float* y = (float*)d_out;
    fwht_k1<<<dim3(NB * (NR / 64)), dim3(512), 0, stream>>>(x, y);
    fwht_k2<<<dim3(NB * 64), dim3(128), 0, stream>>>(y);
}